// Round 1
// baseline (330.580 us; speedup 1.0000x reference)
//
#include <hip/hip_runtime.h>

#define N_NODES 50000
#define N_EDGES 800000
#define D 64

// ---------------------------------------------------------------------------
// Kernel 1: xw = x @ W   (50000x64 @ 64x64)
// Block = 256 threads: col = tid&63, row-in-group = tid>>6 (4 rows/pass),
// 16 rows per block. W staged once in LDS (16 KB), x rows staged per pass.
// ---------------------------------------------------------------------------
__global__ void xw_kernel(const float* __restrict__ x, const float* __restrict__ W,
                          float* __restrict__ xw) {
    __shared__ float Ws[D * D];
    __shared__ float xs[4][D];
    int tid = threadIdx.x;
    for (int i = tid; i < D * D; i += 256) Ws[i] = W[i];
    __syncthreads();

    int col = tid & 63;
    int r   = tid >> 6;
    int rowBase = blockIdx.x * 16;

    for (int g = 0; g < 4; ++g) {
        int row = rowBase + g * 4 + r;
        __syncthreads();                       // protect xs from previous pass
        if (row < N_NODES) xs[r][col] = x[row * D + col];
        __syncthreads();
        if (row < N_NODES) {
            float sum = 0.f;
            #pragma unroll
            for (int k = 0; k < D; ++k)
                sum = fmaf(xs[r][k], Ws[k * D + col], sum);
            xw[row * D + col] = sum;
        }
    }
}

// ---------------------------------------------------------------------------
// Degree: deg[i] = 1 (self-loop) + #incoming edges; then dis = rsqrt(deg).
// ---------------------------------------------------------------------------
__global__ void init_deg(float* __restrict__ deg) {
    int i = blockIdx.x * 256 + threadIdx.x;
    if (i < N_NODES) deg[i] = 1.0f;
}

__global__ void count_deg(const int* __restrict__ dst, float* __restrict__ deg) {
    int e = blockIdx.x * 256 + threadIdx.x;
    if (e < N_EDGES) atomicAdd(&deg[dst[e]], 1.0f);
}

__global__ void rsqrt_deg(float* __restrict__ deg) {
    int i = blockIdx.x * 256 + threadIdx.x;
    if (i < N_NODES) deg[i] = rsqrtf(deg[i]);   // deg >= 1 always (self-loops)
}

// ---------------------------------------------------------------------------
// out[i][d] = b[d] + dis[i]^2 * xw[i][d]      (bias + self-loop message)
// ---------------------------------------------------------------------------
__global__ void init_out(const float* __restrict__ xw, const float* __restrict__ dis,
                         const float* __restrict__ b, float* __restrict__ out) {
    int idx = blockIdx.x * 256 + threadIdx.x;
    if (idx < N_NODES * D) {
        int i = idx >> 6;
        int d = idx & 63;
        float di = dis[i];
        out[idx] = b[d] + di * di * xw[idx];
    }
}

// ---------------------------------------------------------------------------
// Scatter: one wave (64 lanes) per edge. lane = feature dim.
// out[dst][lane] += dis[src]*dis[dst] * xw[src][lane]
// Gathers and atomics are coalesced 256B per edge; dis reads are broadcasts.
// ---------------------------------------------------------------------------
__global__ void scatter_edges(const int* __restrict__ src, const int* __restrict__ dst,
                              const float* __restrict__ dis, const float* __restrict__ xw,
                              float* __restrict__ out) {
    int e    = blockIdx.x * 4 + (threadIdx.x >> 6);
    int lane = threadIdx.x & 63;
    if (e < N_EDGES) {
        int s = src[e];
        int t = dst[e];
        float norm = dis[s] * dis[t];
        atomicAdd(&out[t * D + lane], norm * xw[s * D + lane]);
    }
}

__global__ void relu_kernel(float* __restrict__ out) {
    int i = blockIdx.x * 256 + threadIdx.x;
    if (i < N_NODES * D) out[i] = fmaxf(out[i], 0.0f);
}

// ---------------------------------------------------------------------------
extern "C" void kernel_launch(void* const* d_in, const int* in_sizes, int n_in,
                              void* d_out, int out_size, void* d_ws, size_t ws_size,
                              hipStream_t stream) {
    const float* x  = (const float*)d_in[0];
    const int*   ei = (const int*)d_in[1];      // [2, E] flat: src then dst
    const float* W  = (const float*)d_in[2];
    const float* b  = (const float*)d_in[3];

    const int* src = ei;
    const int* dst = ei + N_EDGES;

    float* out = (float*)d_out;
    float* xw  = (float*)d_ws;                  // N_NODES * D floats (12.8 MB)
    float* deg = xw + (size_t)N_NODES * D;      // N_NODES floats (becomes dis in-place)

    xw_kernel<<<(N_NODES + 15) / 16, 256, 0, stream>>>(x, W, xw);
    init_deg<<<(N_NODES + 255) / 256, 256, 0, stream>>>(deg);
    count_deg<<<(N_EDGES + 255) / 256, 256, 0, stream>>>(dst, deg);
    rsqrt_deg<<<(N_NODES + 255) / 256, 256, 0, stream>>>(deg);
    init_out<<<(N_NODES * D + 255) / 256, 256, 0, stream>>>(xw, deg, b, out);
    scatter_edges<<<(N_EDGES + 3) / 4, 256, 0, stream>>>(src, dst, deg, xw, out);
    relu_kernel<<<(N_NODES * D + 255) / 256, 256, 0, stream>>>(out);
}

// Round 2
// 236.207 us; speedup vs baseline: 1.3995x; 1.3995x over previous
//
#include <hip/hip_runtime.h>

#define N_NODES 50000
#define N_EDGES 800000
#define D 64
#define SCAN_CHUNK 1024                                   // 256 threads x 4 elems
#define NB_SCAN ((N_NODES + SCAN_CHUNK - 1) / SCAN_CHUNK) // 49

// ---------------------------------------------------------------------------
// CSR build: counts -> exclusive scan -> fill. All int32.
// ---------------------------------------------------------------------------
__global__ void zero_counts(int* __restrict__ counts) {
    int i = blockIdx.x * 256 + threadIdx.x;
    if (i < N_NODES) counts[i] = 0;
}

__global__ void hist_kernel(const int* __restrict__ dst, int* __restrict__ counts) {
    int e = blockIdx.x * 256 + threadIdx.x;
    if (e < N_EDGES) atomicAdd(&counts[dst[e]], 1);
}

// Phase 1: per-block exclusive scan of 1024 counts (4/thread) + block total.
__global__ void scan_phase1(const int* __restrict__ counts, int* __restrict__ offsets,
                            int* __restrict__ partials) {
    __shared__ int ts[256];
    int tid  = threadIdx.x;
    int base = blockIdx.x * SCAN_CHUNK + tid * 4;
    int v[4];
    int sum = 0;
    #pragma unroll
    for (int j = 0; j < 4; ++j) {
        v[j] = (base + j < N_NODES) ? counts[base + j] : 0;
        sum += v[j];
    }
    ts[tid] = sum;
    __syncthreads();
    // Hillis-Steele inclusive scan over the 256 thread sums
    for (int off = 1; off < 256; off <<= 1) {
        int t = (tid >= off) ? ts[tid - off] : 0;
        __syncthreads();
        if (tid >= off) ts[tid] += t;
        __syncthreads();
    }
    int run = ts[tid] - sum;  // exclusive prefix for this thread's chunk
    #pragma unroll
    for (int j = 0; j < 4; ++j) {
        if (base + j < N_NODES) offsets[base + j] = run;
        run += v[j];
    }
    if (tid == 255) partials[blockIdx.x] = ts[255];
}

// Phase 2: sequential exclusive scan of the 49 block totals (1 thread, trivial).
__global__ void scan_phase2(int* __restrict__ partials) {
    if (threadIdx.x == 0 && blockIdx.x == 0) {
        int run = 0;
        for (int i = 0; i < NB_SCAN; ++i) {
            int t = partials[i];
            partials[i] = run;
            run += t;
        }
    }
}

// Phase 3: finalize offsets, copy to cursor, compute dis = rsqrt(deg+1).
__global__ void scan_phase3(int* __restrict__ offsets, const int* __restrict__ partials,
                            int* __restrict__ cursor, const int* __restrict__ counts,
                            float* __restrict__ dis) {
    int i = blockIdx.x * 256 + threadIdx.x;
    if (i < N_NODES) {
        int off = offsets[i] + partials[i >> 10];
        offsets[i] = off;
        cursor[i]  = off;
        dis[i]     = rsqrtf((float)counts[i] + 1.0f);  // +1 self-loop
    }
}

__global__ void fill_csr(const int* __restrict__ src, const int* __restrict__ dst,
                         int* __restrict__ cursor, int* __restrict__ csr_src) {
    int e = blockIdx.x * 256 + threadIdx.x;
    if (e < N_EDGES) {
        int t   = dst[e];
        int pos = atomicAdd(&cursor[t], 1);
        csr_src[pos] = src[e];
    }
}

// ---------------------------------------------------------------------------
// xws = dis[row] * (x @ W)   — dis folded in so the gather loop needs only xws
// ---------------------------------------------------------------------------
__global__ void xws_kernel(const float* __restrict__ x, const float* __restrict__ W,
                           const float* __restrict__ dis, float* __restrict__ xws) {
    __shared__ float Ws[D * D];
    __shared__ float xs[4][D];
    int tid = threadIdx.x;
    for (int i = tid; i < D * D; i += 256) Ws[i] = W[i];
    __syncthreads();

    int col = tid & 63;
    int r   = tid >> 6;
    int rowBase = blockIdx.x * 16;

    for (int g = 0; g < 4; ++g) {
        int row = rowBase + g * 4 + r;
        __syncthreads();
        if (row < N_NODES) xs[r][col] = x[row * D + col];
        __syncthreads();
        if (row < N_NODES) {
            float sum = 0.f;
            #pragma unroll
            for (int k = 0; k < D; ++k)
                sum = fmaf(xs[r][k], Ws[k * D + col], sum);
            xws[row * D + col] = dis[row] * sum;
        }
    }
}

// ---------------------------------------------------------------------------
// Gather: one wave per node, lane = feature.
// out[i] = relu(b + dis_i * (xws_i + sum_{j in N(i)} xws_j))
// ---------------------------------------------------------------------------
__global__ void gather_out(const int* __restrict__ csr_src, const int* __restrict__ offsets,
                           const int* __restrict__ counts, const float* __restrict__ dis,
                           const float* __restrict__ xws, const float* __restrict__ b,
                           float* __restrict__ out) {
    int wid  = (blockIdx.x * 256 + threadIdx.x) >> 6;
    int lane = threadIdx.x & 63;
    if (wid >= N_NODES) return;

    int   start = offsets[wid];
    int   cnt   = counts[wid];
    float di    = dis[wid];
    float acc   = xws[wid * D + lane];  // self-loop term (dis_i already folded in)

    int k = 0;
    for (; k + 1 < cnt; k += 2) {       // 2 independent loads per iter for MLP
        int s0 = csr_src[start + k];
        int s1 = csr_src[start + k + 1];
        acc += xws[s0 * D + lane];
        acc += xws[s1 * D + lane];
    }
    if (k < cnt) {
        int s = csr_src[start + k];
        acc += xws[s * D + lane];
    }
    out[wid * D + lane] = fmaxf(b[lane] + di * acc, 0.0f);
}

// ---------------------------------------------------------------------------
extern "C" void kernel_launch(void* const* d_in, const int* in_sizes, int n_in,
                              void* d_out, int out_size, void* d_ws, size_t ws_size,
                              hipStream_t stream) {
    const float* x  = (const float*)d_in[0];
    const int*   ei = (const int*)d_in[1];   // [2, E] flat: src then dst
    const float* W  = (const float*)d_in[2];
    const float* b  = (const float*)d_in[3];

    const int* src = ei;
    const int* dst = ei + N_EDGES;

    float* out = (float*)d_out;

    // workspace layout
    float* xws     = (float*)d_ws;                      // N*D floats   (12.8 MB)
    float* dis     = xws + (size_t)N_NODES * D;         // N floats
    int*   counts  = (int*)(dis + N_NODES);             // N ints
    int*   offsets = counts + N_NODES;                  // N ints
    int*   cursor  = offsets + N_NODES;                 // N ints
    int*   partials= cursor + N_NODES;                  // NB_SCAN ints
    int*   csr_src = partials + NB_SCAN;                // E ints (3.2 MB)

    zero_counts<<<(N_NODES + 255) / 256, 256, 0, stream>>>(counts);
    hist_kernel<<<(N_EDGES + 255) / 256, 256, 0, stream>>>(dst, counts);
    scan_phase1<<<NB_SCAN, 256, 0, stream>>>(counts, offsets, partials);
    scan_phase2<<<1, 64, 0, stream>>>(partials);
    scan_phase3<<<(N_NODES + 255) / 256, 256, 0, stream>>>(offsets, partials, cursor, counts, dis);
    xws_kernel<<<(N_NODES + 15) / 16, 256, 0, stream>>>(x, W, dis, xws);
    fill_csr<<<(N_EDGES + 255) / 256, 256, 0, stream>>>(src, dst, cursor, csr_src);
    gather_out<<<(N_NODES * 64 + 255) / 256, 256, 0, stream>>>(csr_src, offsets, counts, dis, xws, b, out);
}